// Round 2
// baseline (282.560 us; speedup 1.0000x reference)
//
#include <hip/hip_runtime.h>
#include <hip/hip_fp16.h>
#include <math.h>

typedef _Float16 f16;
typedef _Float16 f16x8 __attribute__((ext_vector_type(8)));
typedef _Float16 f16x4v __attribute__((ext_vector_type(4)));
typedef float f32x4 __attribute__((ext_vector_type(4)));

#define B_SZ 16384
#define D_INP 128
#define HID 2048
#define DIMS 9
#define OUTC 54   // DIM*(N_BASIS+1)
#define OUTP 64   // padded to MFMA tile
#define NZ3 4     // split-K factor for GEMM3

// ---------------- async global->LDS (16B per lane, wave-uniform LDS base) ----
__device__ __forceinline__ void load_lds16(const f16* g, f16* l) {
    __builtin_amdgcn_global_load_lds(
        (__attribute__((address_space(1))) void*)(g),
        (__attribute__((address_space(3))) void*)(l),
        16, 0, 0);
}

__device__ __forceinline__ float fast_tanh(float x) {
    // tanh(x) = 1 - 2/(exp(2x)+1); exp via v_exp_f32 (exp2)
    float e = __builtin_amdgcn_exp2f(2.885390081777927f * x);  // e^(2x)
    return 1.0f - 2.0f * __builtin_amdgcn_rcpf(e + 1.0f);
}

// ---------------- fused fp32 -> fp16 converts (W0, W1, Wl-pad) --------------
#define N4_W0  (HID * D_INP / 4)       // 65536
#define N4_W1  (HID * HID / 4)         // 1048576
#define N4_WL  (OUTP * HID / 4)        // 32768
// total = 1146880 = 256 * 4480 exactly (no tail threads)
__global__ __launch_bounds__(256) void cvt_fused_kernel(
    const float* __restrict__ W0, const float* __restrict__ W1,
    const float* __restrict__ Wl,
    f16* __restrict__ w0q, f16* __restrict__ w1q, f16* __restrict__ wlq)
{
    int i = blockIdx.x * 256 + threadIdx.x;
    const float* s; f16* d; int j;
    if (i < N4_W0) { s = W0; d = w0q; j = i; }
    else if (i < N4_W0 + N4_W1) { s = W1; d = w1q; j = i - N4_W0; }
    else {
        // Wl pad: dest (64 x 2048), source (54 x 2048)
        j = i - N4_W0 - N4_W1;
        int e0 = j * 4, row = e0 >> 11, col = e0 & (HID - 1);
        f16x4v o;
        if (row < OUTC) {
            float4 v = ((const float4*)Wl)[(row * HID + col) >> 2];
            o.x = (f16)v.x; o.y = (f16)v.y; o.z = (f16)v.z; o.w = (f16)v.w;
        } else {
            o.x = (f16)0.f; o.y = (f16)0.f; o.z = (f16)0.f; o.w = (f16)0.f;
        }
        ((f16x4v*)wlq)[j] = o;
        return;
    }
    float4 v = ((const float4*)s)[j];
    f16x4v o;
    o.x = (f16)v.x; o.y = (f16)v.y; o.z = (f16)v.z; o.w = (f16)v.w;
    ((f16x4v*)d)[j] = o;
}

// ---------------- NT GEMM: C = A(MxK) * B(NxK)^T, fp16 in / fp32 acc -------
// (retained for GEMM3 only; GEMM2 uses the 8-phase 256^2 kernel below)
// 16x16x32 MFMA; BK=64 (128B LDS rows); 16B-chunk c of row r at slot c^(r&7).
template <int BN, int EPI>
__global__ __launch_bounds__(256, 2) void gemm_nt(
    const f16* __restrict__ A, const f16* __restrict__ Bm,
    const float* __restrict__ bias, void* __restrict__ Cout,
    int M, int N, int K, int bias_n)
{
    constexpr int BM = 128, BK = 64;
    constexpr int NI = BN / 32;                 // 16-col subtiles per wave
    __shared__ __align__(16) f16 sa[BM * BK];
    __shared__ __align__(16) f16 sb[BN * BK];

    const int tid  = threadIdx.x;
    const int lane = tid & 63;
    const int wave = tid >> 6;
    const int wm = wave >> 1, wn = wave & 1;

    // L2-locality block swizzle: 8 m-tiles per group, n fastest within group
    const int flat = blockIdx.x + blockIdx.y * gridDim.x;
    const int gsz  = 8 * gridDim.y;
    const int grp  = flat / gsz;
    const int rem  = flat - grp * gsz;
    const int m0 = (grp * 8 + (rem & 7)) * BM;
    const int n0 = (rem >> 3) * BN;

    const int k_len = K / gridDim.z;
    const int k_beg = blockIdx.z * k_len;
    const int k_end = k_beg + k_len;

    f32x4 acc[4][NI];
    #pragma unroll
    for (int i = 0; i < 4; ++i)
        #pragma unroll
        for (int j = 0; j < NI; ++j) acc[i][j] = (f32x4){0.f, 0.f, 0.f, 0.f};

    const int r8 = lane >> 3;                        // row within 8-row staging group
    const int cg = (((lane & 7) ^ r8) << 3);         // swizzled global k-chunk (elems)

    for (int k0 = k_beg; k0 < k_end; k0 += BK) {
        #pragma unroll
        for (int c = 0; c < (BM * BK * 2) / 4096; ++c) {
            int o = c * 4096 + wave * 1024;          // wave-uniform LDS byte base
            const f16* gp = A + (size_t)(m0 + (o >> 7) + r8) * K + k0 + cg;
            load_lds16(gp, (f16*)((char*)sa + o));
        }
        #pragma unroll
        for (int c = 0; c < (BN * BK * 2) / 4096; ++c) {
            int o = c * 4096 + wave * 1024;
            const f16* gp = Bm + (size_t)(n0 + (o >> 7) + r8) * K + k0 + cg;
            load_lds16(gp, (f16*)((char*)sb + o));
        }
        __syncthreads();   // drains vmcnt (global_load_lds) + barrier

        #pragma unroll
        for (int kc = 0; kc < 2; ++kc) {
            f16x8 af[4], bf[NI];
            #pragma unroll
            for (int mi = 0; mi < 4; ++mi) {
                int ar = wm * 64 + mi * 16 + (lane & 15);
                af[mi] = *(const f16x8*)&sa[ar * 64 + ((((kc << 2) | (lane >> 4)) ^ (ar & 7)) << 3)];
            }
            #pragma unroll
            for (int ni = 0; ni < NI; ++ni) {
                int br = wn * (BN / 2) + ni * 16 + (lane & 15);
                bf[ni] = *(const f16x8*)&sb[br * 64 + ((((kc << 2) | (lane >> 4)) ^ (br & 7)) << 3)];
            }
            #pragma unroll
            for (int mi = 0; mi < 4; ++mi)
                #pragma unroll
                for (int ni = 0; ni < NI; ++ni)
                    acc[mi][ni] = __builtin_amdgcn_mfma_f32_16x16x32_f16(af[mi], bf[ni], acc[mi][ni], 0, 0, 0);
        }
        __syncthreads();   // protect LDS before next stage
    }

    // epilogue: C/D layout col = lane&15, row = (lane>>4)*4 + r
    const int crow0 = m0 + wm * 64 + (lane >> 4) * 4;
    const int ccol0 = n0 + wn * (BN / 2) + (lane & 15);
    if (EPI == 0) {
        f16* C = (f16*)Cout;
        #pragma unroll
        for (int mi = 0; mi < 4; ++mi)
            #pragma unroll
            for (int ni = 0; ni < NI; ++ni) {
                int col = ccol0 + ni * 16;
                float bv = bias[col];
                #pragma unroll
                for (int r2 = 0; r2 < 4; ++r2) {
                    float v = fast_tanh(acc[mi][ni][r2] + bv);
                    C[(size_t)(crow0 + mi * 16 + r2) * N + col] = (f16)v;
                }
            }
    } else {
        float* C = (float*)Cout + (size_t)blockIdx.z * M * N;
        #pragma unroll
        for (int mi = 0; mi < 4; ++mi)
            #pragma unroll
            for (int ni = 0; ni < NI; ++ni) {
                int col = ccol0 + ni * 16;
                float bv = (blockIdx.z == 0 && col < bias_n) ? bias[col] * 100.0f : 0.0f;
                #pragma unroll
                for (int r2 = 0; r2 < 4; ++r2) {
                    float v = acc[mi][ni][r2] * 100.0f + bv;
                    C[(size_t)(crow0 + mi * 16 + r2) * N + col] = v;
                }
            }
    }
}

// ---------------- GEMM2: 256x256-tile 8-phase pipelined NT GEMM, f16 --------
// C_f16 = tanh(A(16384x2048) @ W1(2048x2048)^T + b1)
// R1 post-mortem fix: round-1 version pinned the scheduler with per-phase
// sched_barrier(0) + "memory" clobbers (m141 failure mode: 874->510 TF).
// Now: bare lgkmcnt(0) (template-exact), zero-cost compiler fences around
// each s_barrier to keep the vmcnt ledger's ISSUE ORDER deterministic
// across phase boundaries, full scheduling freedom within a phase.
// Stage ledger (iter j, tiles t=2j in buf0 / t+1 in buf1):
//   ph1: A0(t+1)->buf1   ph2: A1(t+1)->buf1   (buf1 A reads ended prev ph8)
//   ph3: B0(t+2)->buf0   ph4: B1(t+2)->buf0   (buf0 B reads front-loaded ph1-2)
//   ph5: A0(t+2)->buf0   ph6: A1(t+2)->buf0   (buf0 A reads ended ph4)
//   ph7: B0(t+3)->buf1   ph8: B1(t+3)->buf1   (buf1 B reads front-loaded ph5-6)
//   vmcnt(4)@ph4: leaves ph3+ph4 (4 loads/wave) in flight -> tile t+1 landed.
//   vmcnt(4)@ph8: leaves ph7+ph8 in flight -> tile t+2 landed.
// Last iteration peeled; vmcnt(0) at its ph4.
#define G2_K 2048
#define G2_N 2048

__global__ __launch_bounds__(512, 2) void gemm2_8ph(
    const f16* __restrict__ A, const f16* __restrict__ Bm,
    const float* __restrict__ bias, f16* __restrict__ C)
{
    constexpr int K = G2_K, N = G2_N;
    constexpr int NT = K / 64;                 // 32 K-tiles, 16 iterations
    __shared__ __align__(16) f16 sa[2][256 * 64];
    __shared__ __align__(16) f16 sb[2][256 * 64];

    const int tid  = threadIdx.x;
    const int lane = tid & 63;
    const int wave = tid >> 6;                 // 0..7
    const int wm   = wave >> 2;                // 0..1 (128-row half)
    const int wn   = wave & 3;                 // 0..3 (64-col slice)
    const int l15  = lane & 15;
    const int l4   = lane >> 4;
    const int r8   = lane >> 3;
    const int cg   = (((lane & 7) ^ r8) << 3); // pre-swizzled global k-chunk

    // XCD-bijective swizzle: 512 wgs = 8 XCDs x 64; n fastest within an XCD
    // chunk so 8 consecutive-in-time blocks share one A row-panel (L2 hit).
    const int flat = blockIdx.x;
    const int wgid = (flat & 7) * 64 + (flat >> 3);
    const int m0 = (wgid >> 3) * 256;
    const int n0 = (wgid & 7) * 256;

    // per-lane global staging bases (row = base + h*128 + c*64; k = tile*64+cg)
    const f16* aSt = A  + (size_t)(m0 + wave * 8 + r8) * K + cg;
    const f16* bSt = Bm + (size_t)(n0 + wave * 8 + r8) * K + cg;

    f32x4 acc[8][4];
    #pragma unroll
    for (int i = 0; i < 8; ++i)
        #pragma unroll
        for (int j = 0; j < 4; ++j) acc[i][j] = (f32x4){0.f, 0.f, 0.f, 0.f};

    f16x8 af0[4], af1[4], bf0[4], bf1[4];

// --- macros (all indices compile-time except tile) ---
#define STAGE_A(bufi, tile, h) { \
    load_lds16(aSt + (size_t)((h) * 128) * K + (tile) * 64, \
               (f16*)((char*)sa[bufi] + (h) * 16384 + wave * 1024)); \
    load_lds16(aSt + (size_t)((h) * 128 + 64) * K + (tile) * 64, \
               (f16*)((char*)sa[bufi] + (h) * 16384 + 8192 + wave * 1024)); }
#define STAGE_B(bufi, tile, h) { \
    load_lds16(bSt + (size_t)((h) * 128) * K + (tile) * 64, \
               (f16*)((char*)sb[bufi] + (h) * 16384 + wave * 1024)); \
    load_lds16(bSt + (size_t)((h) * 128 + 64) * K + (tile) * 64, \
               (f16*)((char*)sb[bufi] + (h) * 16384 + 8192 + wave * 1024)); }
#define LDA4(dst, bufi, kc, mh) { \
    _Pragma("unroll") \
    for (int mi = 0; mi < 4; ++mi) { \
        int ar = wm * 128 + (mh) * 64 + mi * 16 + l15; \
        dst[mi] = *(const f16x8*)&sa[bufi][ar * 64 + (((((kc) << 2) | l4) ^ (ar & 7)) << 3)]; \
    } }
#define LDB4(dst, bufi, kc) { \
    _Pragma("unroll") \
    for (int ni = 0; ni < 4; ++ni) { \
        int br = wn * 64 + ni * 16 + l15; \
        dst[ni] = *(const f16x8*)&sb[bufi][br * 64 + (((((kc) << 2) | l4) ^ (br & 7)) << 3)]; \
    } }
#define MFMA16(aset, bset, mh) { \
    _Pragma("unroll") \
    for (int mi = 0; mi < 4; ++mi) \
        _Pragma("unroll") \
        for (int ni = 0; ni < 4; ++ni) \
            acc[(mh) * 4 + mi][ni] = __builtin_amdgcn_mfma_f32_16x16x32_f16( \
                aset[mi], bset[ni], acc[(mh) * 4 + mi][ni], 0, 0, 0); }
// Barrier with zero-instruction compiler fences: memory ops (stage/ds_read)
// cannot migrate across a phase boundary (vmcnt ledger stays exact), but the
// scheduler remains free WITHIN the phase. No sched_barrier, no hard clobber
// on the lgkmcnt drain (m141: order-pinning costs ~40%).
#define BAR   { asm volatile("" ::: "memory"); \
                __builtin_amdgcn_s_barrier(); \
                asm volatile("" ::: "memory"); }
#define WLG   asm volatile("s_waitcnt lgkmcnt(0)")
#define WVM4  asm volatile("s_waitcnt vmcnt(4)" ::: "memory")
#define WVM0  asm volatile("s_waitcnt vmcnt(0)" ::: "memory")
#define PRIO1 __builtin_amdgcn_s_setprio(1)
#define PRIO0 __builtin_amdgcn_s_setprio(0)

    // ---- prologue: tile 0 fully + tile 1 B halves (12 loads/wave) ----
    STAGE_A(0, 0, 0); STAGE_A(0, 0, 1);
    STAGE_B(0, 0, 0); STAGE_B(0, 0, 1);
    STAGE_B(1, 1, 0); STAGE_B(1, 1, 1);
    WVM4;   // oldest 8 (= tile 0) landed; B(tile1) may remain in flight
    BAR;

    #pragma unroll 1
    for (int j = 0; j < NT / 2 - 1; ++j) {
        const int t = 2 * j;
        // PH1: read A(kc0,mh0)+B(kc0) of buf0; stage A0(t+1)->buf1
        LDA4(af0, 0, 0, 0); LDB4(bf0, 0, 0);
        STAGE_A(1, t + 1, 0);
        BAR; WLG; PRIO1; MFMA16(af0, bf0, 0); PRIO0; BAR;
        // PH2: read A(kc0,mh1)+B(kc1); stage A1(t+1)->buf1
        LDA4(af1, 0, 0, 1); LDB4(bf1, 0, 1);
        STAGE_A(1, t + 1, 1);
        BAR; WLG; PRIO1; MFMA16(af1, bf0, 1); PRIO0; BAR;
        // PH3: read A(kc1,mh0); stage B0(t+2)->buf0 (buf0 B fully read ph1-2)
        LDA4(af0, 0, 1, 0);
        STAGE_B(0, t + 2, 0);
        BAR; WLG; PRIO1; MFMA16(af0, bf1, 0); PRIO0; BAR;
        // PH4: read A(kc1,mh1); stage B1(t+2)->buf0; certify tile t+1
        LDA4(af1, 0, 1, 1);
        STAGE_B(0, t + 2, 1);
        BAR; WLG; PRIO1; MFMA16(af1, bf1, 1); PRIO0; WVM4; BAR;
        // PH5: buf1 (tile t+1)
        LDA4(af0, 1, 0, 0); LDB4(bf0, 1, 0);
        STAGE_A(0, t + 2, 0);
        BAR; WLG; PRIO1; MFMA16(af0, bf0, 0); PRIO0; BAR;
        // PH6
        LDA4(af1, 1, 0, 1); LDB4(bf1, 1, 1);
        STAGE_A(0, t + 2, 1);
        BAR; WLG; PRIO1; MFMA16(af1, bf0, 1); PRIO0; BAR;
        // PH7
        LDA4(af0, 1, 1, 0);
        STAGE_B(1, t + 3, 0);
        BAR; WLG; PRIO1; MFMA16(af0, bf1, 0); PRIO0; BAR;
        // PH8: certify tile t+2
        LDA4(af1, 1, 1, 1);
        STAGE_B(1, t + 3, 1);
        BAR; WLG; PRIO1; MFMA16(af1, bf1, 1); PRIO0; WVM4; BAR;
    }
    // ---- last iteration (tiles NT-2 in buf0, NT-1 in buf1) ----
    {
        LDA4(af0, 0, 0, 0); LDB4(bf0, 0, 0);
        STAGE_A(1, NT - 1, 0);
        BAR; WLG; PRIO1; MFMA16(af0, bf0, 0); PRIO0; BAR;

        LDA4(af1, 0, 0, 1); LDB4(bf1, 0, 1);
        STAGE_A(1, NT - 1, 1);
        BAR; WLG; PRIO1; MFMA16(af1, bf0, 1); PRIO0; BAR;

        LDA4(af0, 0, 1, 0);
        BAR; WLG; PRIO1; MFMA16(af0, bf1, 0); PRIO0; BAR;

        LDA4(af1, 0, 1, 1);
        BAR; WLG; PRIO1; MFMA16(af1, bf1, 1); PRIO0; WVM0; BAR;  // all of NT-1 landed

        LDA4(af0, 1, 0, 0); LDB4(bf0, 1, 0);
        BAR; WLG; PRIO1; MFMA16(af0, bf0, 0); PRIO0; BAR;

        LDA4(af1, 1, 0, 1); LDB4(bf1, 1, 1);
        BAR; WLG; PRIO1; MFMA16(af1, bf0, 1); PRIO0; BAR;

        LDA4(af0, 1, 1, 0);
        BAR; WLG; PRIO1; MFMA16(af0, bf1, 0); PRIO0; BAR;

        LDA4(af1, 1, 1, 1);
        BAR; WLG; PRIO1; MFMA16(af1, bf1, 1); PRIO0; BAR;
    }

#undef STAGE_A
#undef STAGE_B
#undef LDA4
#undef LDB4
#undef MFMA16
#undef BAR
#undef WLG
#undef WVM4
#undef WVM0
#undef PRIO1
#undef PRIO0

    // ---- epilogue: C/D layout col = lane&15, row = (lane>>4)*4 + r ----
    const int crow0 = m0 + wm * 128 + l4 * 4;
    const int ccol0 = n0 + wn * 64 + l15;
    #pragma unroll
    for (int mi = 0; mi < 8; ++mi)
        #pragma unroll
        for (int ni = 0; ni < 4; ++ni) {
            int col = ccol0 + ni * 16;
            float bv = bias[col];
            #pragma unroll
            for (int r2 = 0; r2 < 4; ++r2) {
                float v = fast_tanh(acc[mi][ni][r2] + bv);
                C[(size_t)(crow0 + mi * 16 + r2) * N + col] = (f16)v;
            }
        }
}

// ---------------- GEMM1: A is fp32 (raw input), staged with in-reg convert ---
// C_f16 = tanh(A(16384x128_f32) @ W0q(2048x128_f16)^T + b0); K = 128 (2 iters)
__global__ __launch_bounds__(256, 2) void gemm1_f32a(
    const float* __restrict__ A, const f16* __restrict__ Bm,
    const float* __restrict__ bias, f16* __restrict__ C)
{
    constexpr int BM = 128, BK = 64, BN = 128, NI = 4;
    constexpr int N = HID, K = D_INP;
    __shared__ __align__(16) f16 sa[BM * BK];
    __shared__ __align__(16) f16 sb[BN * BK];

    const int tid  = threadIdx.x;
    const int lane = tid & 63;
    const int wave = tid >> 6;
    const int wm = wave >> 1, wn = wave & 1;

    const int flat = blockIdx.x + blockIdx.y * gridDim.x;
    const int gsz  = 8 * gridDim.y;
    const int grp  = flat / gsz;
    const int rem  = flat - grp * gsz;
    const int m0 = (grp * 8 + (rem & 7)) * BM;
    const int n0 = (rem >> 3) * BN;

    f32x4 acc[4][NI];
    #pragma unroll
    for (int i = 0; i < 4; ++i)
        #pragma unroll
        for (int j = 0; j < NI; ++j) acc[i][j] = (f32x4){0.f, 0.f, 0.f, 0.f};

    const int r8 = lane >> 3;
    const int cg = (((lane & 7) ^ r8) << 3);

    for (int k0 = 0; k0 < K; k0 += BK) {
        // A: fp32 global -> convert -> ds_write_b128 (lane-contiguous, conflict-free)
        #pragma unroll
        for (int c = 0; c < (BM * BK * 2) / 4096; ++c) {
            int o = c * 4096 + wave * 1024;
            const float* gp = A + (size_t)(m0 + (o >> 7) + r8) * K + k0 + cg;
            float4 v0 = *(const float4*)gp;
            float4 v1 = *(const float4*)(gp + 4);
            f16x8 h;
            h[0] = (f16)v0.x; h[1] = (f16)v0.y; h[2] = (f16)v0.z; h[3] = (f16)v0.w;
            h[4] = (f16)v1.x; h[5] = (f16)v1.y; h[6] = (f16)v1.z; h[7] = (f16)v1.w;
            *(f16x8*)((char*)sa + o + (lane << 4)) = h;
        }
        // B: pre-converted f16 via async DMA
        #pragma unroll
        for (int c = 0; c < (BN * BK * 2) / 4096; ++c) {
            int o = c * 4096 + wave * 1024;
            const f16* gp = Bm + (size_t)(n0 + (o >> 7) + r8) * K + k0 + cg;
            load_lds16(gp, (f16*)((char*)sb + o));
        }
        __syncthreads();

        #pragma unroll
        for (int kc = 0; kc < 2; ++kc) {
            f16x8 af[4], bf[NI];
            #pragma unroll
            for (int mi = 0; mi < 4; ++mi) {
                int ar = wm * 64 + mi * 16 + (lane & 15);
                af[mi] = *(const f16x8*)&sa[ar * 64 + ((((kc << 2) | (lane >> 4)) ^ (ar & 7)) << 3)];
            }
            #pragma unroll
            for (int ni = 0; ni < NI; ++ni) {
                int br = wn * 64 + ni * 16 + (lane & 15);
                bf[ni] = *(const f16x8*)&sb[br * 64 + ((((kc << 2) | (lane >> 4)) ^ (br & 7)) << 3)];
            }
            #pragma unroll
            for (int mi = 0; mi < 4; ++mi)
                #pragma unroll
                for (int ni = 0; ni < NI; ++ni)
                    acc[mi][ni] = __builtin_amdgcn_mfma_f32_16x16x32_f16(af[mi], bf[ni], acc[mi][ni], 0, 0, 0);
        }
        __syncthreads();
    }

    const int crow0 = m0 + wm * 64 + (lane >> 4) * 4;
    const int ccol0 = n0 + wn * 64 + (lane & 15);
    #pragma unroll
    for (int mi = 0; mi < 4; ++mi)
        #pragma unroll
        for (int ni = 0; ni < NI; ++ni) {
            int col = ccol0 + ni * 16;
            float bv = bias[col];
            #pragma unroll
            for (int r2 = 0; r2 < 4; ++r2) {
                float v = fast_tanh(acc[mi][ni][r2] + bv);
                C[(size_t)(crow0 + mi * 16 + r2) * N + col] = (f16)v;
            }
        }
}

// ---------------- DMP Euler integration (sums NZ3 partial slices) -----------
// out3p: (NZ3, B, 64) partial MLP outputs; input: (B, 128); out: (B, 9, 10)
__global__ __launch_bounds__(256) void integrate_kernel(
    const float* __restrict__ out3p, const float* __restrict__ input,
    float* __restrict__ out)
{
    __shared__ float g[500];
    {
        int k = threadIdx.x;
        if (k < 100) {
            // x after k+1 steps of x *= 0.99  (closed form)
            float x = expf(-0.010050335853501441f * (float)(k + 1));
            float psi[5], ssum = 0.0f;
            #pragma unroll
            for (int n = 0; n < 5; ++n) {
                float c = expf(-0.25f * (float)n);
                float h = 11.180339887498949f / c;   // N^1.5 / c / A_X
                float dx = x - c;
                psi[n] = expf(-h * dx * dx);
                ssum += psi[n];
            }
            float inv = x / ssum;
            #pragma unroll
            for (int n = 0; n < 5; ++n) g[k * 5 + n] = psi[n] * inv;
        }
    }
    __syncthreads();

    int r = blockIdx.x * 256 + threadIdx.x;      // 0 .. B*9-1
    int b = r / DIMS, d = r - b * DIMS;

    float goal = 0.f, w0 = 0.f, w1 = 0.f, w2 = 0.f, w3 = 0.f, w4 = 0.f;
    #pragma unroll
    for (int z = 0; z < NZ3; ++z) {
        const float* ob = out3p + (size_t)z * B_SZ * OUTP + (size_t)b * OUTP;
        goal += ob[d];
        w0 += ob[DIMS + d * 5 + 0];
        w1 += ob[DIMS + d * 5 + 1];
        w2 += ob[DIMS + d * 5 + 2];
        w3 += ob[DIMS + d * 5 + 3];
        w4 += ob[DIMS + d * 5 + 4];
    }

    float y = input[(size_t)b * D_INP + 7 + d];    // y0
    float z = input[(size_t)b * D_INP + 22 + d];   // dy0 * TAU (TAU=1)
    const float scale = goal - y;

    float prev = y;
    float* op = out + (size_t)b * (DIMS * 10) + d * 10;
    int j = 0;
    for (int k = 0; k < 100; ++k) {
        const float* gk = &g[k * 5];
        float fx = scale * (w0 * gk[0] + w1 * gk[1] + w2 * gk[2] + w3 * gk[3] + w4 * gk[4]);
        float dz = 25.0f * (6.25f * (goal - y) - z) + fx;   // A_Z=25, B_Z=6.25
        y = y + z * 0.01f;     // dy = z (old z), y += dy*DT
        z = z + dz * 0.01f;
        if ((k % 10) == 9) { op[j] = y - prev; prev = y; ++j; }
    }
}

// ---------------- launch ----------------
extern "C" void kernel_launch(void* const* d_in, const int* in_sizes, int n_in,
                              void* d_out, int out_size, void* d_ws, size_t ws_size,
                              hipStream_t stream) {
    (void)in_sizes; (void)n_in; (void)out_size; (void)ws_size;
    const float* input = (const float*)d_in[0];
    const float* W0 = (const float*)d_in[1];
    const float* b0 = (const float*)d_in[2];
    const float* W1 = (const float*)d_in[3];
    const float* b1 = (const float*)d_in[4];
    const float* Wl = (const float*)d_in[5];
    const float* bl = (const float*)d_in[6];
    float* out = (float*)d_out;

    // workspace layout (all 16B-aligned by construction)
    f16* w0q = (f16*)d_ws;                                // 2048*128
    f16* w1q = w0q + (size_t)HID * D_INP;                 // 2048*2048
    f16* wlq = w1q + (size_t)HID * HID;                   // 64*2048
    f16* h1  = wlq + (size_t)OUTP * HID;                  // 16384*2048
    f16* h2  = h1 + (size_t)B_SZ * HID;                   // 16384*2048
    // GEMM3 partial slices overlay h1 (dead after GEMM2): NZ3 * 16384 * 64 f32
    float* out3p = (float*)h1;

    int n4_total = N4_W0 + N4_W1 + N4_WL;
    cvt_fused_kernel<<<(n4_total + 255) / 256, 256, 0, stream>>>(
        W0, W1, Wl, w0q, w1q, wlq);

    // h1 = tanh(input @ W0^T + b0), A staged from fp32 directly
    gemm1_f32a<<<dim3(B_SZ / 128, HID / 128), 256, 0, stream>>>(
        input, w0q, b0, h1);
    // h2 = tanh(h1 @ W1^T + b1) — 256^2 8-phase pipelined kernel
    gemm2_8ph<<<dim3((B_SZ / 256) * (HID / 256)), 512, 0, stream>>>(
        h1, w1q, b1, h2);
    // out3p[z] = (h2 @ Wl^T)*100 slices (+bl*100 on z0); N padded to 64
    gemm_nt<64, 1><<<dim3(B_SZ / 128, 1, NZ3), 256, 0, stream>>>(
        h2, wlq, bl, (void*)out3p, B_SZ, OUTP, HID, OUTC);

    integrate_kernel<<<B_SZ * DIMS / 256, 256, 0, stream>>>(out3p, input, out);
}

// Round 3
// 271.270 us; speedup vs baseline: 1.0416x; 1.0416x over previous
//
#include <hip/hip_runtime.h>
#include <hip/hip_fp16.h>
#include <math.h>

typedef _Float16 f16;
typedef _Float16 f16x8 __attribute__((ext_vector_type(8)));
typedef _Float16 f16x4v __attribute__((ext_vector_type(4)));
typedef float f32x4 __attribute__((ext_vector_type(4)));

#define B_SZ 16384
#define D_INP 128
#define HID 2048
#define DIMS 9
#define OUTC 54   // DIM*(N_BASIS+1)
#define OUTP 64   // padded to MFMA tile
#define NZ3 4     // split-K factor for GEMM3

// ---------------- async global->LDS (16B per lane, wave-uniform LDS base) ----
__device__ __forceinline__ void load_lds16(const f16* g, f16* l) {
    __builtin_amdgcn_global_load_lds(
        (__attribute__((address_space(1))) void*)(g),
        (__attribute__((address_space(3))) void*)(l),
        16, 0, 0);
}

__device__ __forceinline__ float fast_tanh(float x) {
    // tanh(x) = 1 - 2/(exp(2x)+1); exp via v_exp_f32 (exp2)
    float e = __builtin_amdgcn_exp2f(2.885390081777927f * x);  // e^(2x)
    return 1.0f - 2.0f * __builtin_amdgcn_rcpf(e + 1.0f);
}

// ---------------- fused fp32 -> fp16 converts (W0, W1, Wl-pad) --------------
#define N4_W0  (HID * D_INP / 4)       // 65536
#define N4_W1  (HID * HID / 4)         // 1048576
#define N4_WL  (OUTP * HID / 4)        // 32768
// total = 1146880 = 256 * 4480 exactly (no tail threads)
__global__ __launch_bounds__(256) void cvt_fused_kernel(
    const float* __restrict__ W0, const float* __restrict__ W1,
    const float* __restrict__ Wl,
    f16* __restrict__ w0q, f16* __restrict__ w1q, f16* __restrict__ wlq)
{
    int i = blockIdx.x * 256 + threadIdx.x;
    const float* s; f16* d; int j;
    if (i < N4_W0) { s = W0; d = w0q; j = i; }
    else if (i < N4_W0 + N4_W1) { s = W1; d = w1q; j = i - N4_W0; }
    else {
        // Wl pad: dest (64 x 2048), source (54 x 2048)
        j = i - N4_W0 - N4_W1;
        int e0 = j * 4, row = e0 >> 11, col = e0 & (HID - 1);
        f16x4v o;
        if (row < OUTC) {
            float4 v = ((const float4*)Wl)[(row * HID + col) >> 2];
            o.x = (f16)v.x; o.y = (f16)v.y; o.z = (f16)v.z; o.w = (f16)v.w;
        } else {
            o.x = (f16)0.f; o.y = (f16)0.f; o.z = (f16)0.f; o.w = (f16)0.f;
        }
        ((f16x4v*)wlq)[j] = o;
        return;
    }
    float4 v = ((const float4*)s)[j];
    f16x4v o;
    o.x = (f16)v.x; o.y = (f16)v.y; o.z = (f16)v.z; o.w = (f16)v.w;
    ((f16x4v*)d)[j] = o;
}

// ---------------- NT GEMM: C = A(MxK) * B(NxK)^T, fp16 in / fp32 acc -------
// 16x16x32 MFMA; BK=64 (128B LDS rows); 16B-chunk c of row r at slot c^(r&7).
// Conflict-free law (R3 vs R4 measured): row-XOR swizzle + chunk index varying
// per QUARTER-wave (lane>>4) => 0 conflicts.
// Block swizzle: groups of 8 m-tiles x all n-tiles for L2 locality.
// EPI 0: C_f16 = tanh(acc + bias[col])                       (stride N)
// EPI 1: partial slice z: C[z*M*N + row*N+col] = acc*100 (+bias*100 on z==0)
template <int BN, int EPI>
__global__ __launch_bounds__(256, 2) void gemm_nt(
    const f16* __restrict__ A, const f16* __restrict__ Bm,
    const float* __restrict__ bias, void* __restrict__ Cout,
    int M, int N, int K, int bias_n)
{
    constexpr int BM = 128, BK = 64;
    constexpr int NI = BN / 32;                 // 16-col subtiles per wave
    __shared__ __align__(16) f16 sa[BM * BK];
    __shared__ __align__(16) f16 sb[BN * BK];

    const int tid  = threadIdx.x;
    const int lane = tid & 63;
    const int wave = tid >> 6;
    const int wm = wave >> 1, wn = wave & 1;

    // L2-locality block swizzle: 8 m-tiles per group, n fastest within group
    const int flat = blockIdx.x + blockIdx.y * gridDim.x;
    const int gsz  = 8 * gridDim.y;
    const int grp  = flat / gsz;
    const int rem  = flat - grp * gsz;
    const int m0 = (grp * 8 + (rem & 7)) * BM;
    const int n0 = (rem >> 3) * BN;

    const int k_len = K / gridDim.z;
    const int k_beg = blockIdx.z * k_len;
    const int k_end = k_beg + k_len;

    f32x4 acc[4][NI];
    #pragma unroll
    for (int i = 0; i < 4; ++i)
        #pragma unroll
        for (int j = 0; j < NI; ++j) acc[i][j] = (f32x4){0.f, 0.f, 0.f, 0.f};

    const int r8 = lane >> 3;                        // row within 8-row staging group
    const int cg = (((lane & 7) ^ r8) << 3);         // swizzled global k-chunk (elems)

    for (int k0 = k_beg; k0 < k_end; k0 += BK) {
        #pragma unroll
        for (int c = 0; c < (BM * BK * 2) / 4096; ++c) {
            int o = c * 4096 + wave * 1024;          // wave-uniform LDS byte base
            const f16* gp = A + (size_t)(m0 + (o >> 7) + r8) * K + k0 + cg;
            load_lds16(gp, (f16*)((char*)sa + o));
        }
        #pragma unroll
        for (int c = 0; c < (BN * BK * 2) / 4096; ++c) {
            int o = c * 4096 + wave * 1024;
            const f16* gp = Bm + (size_t)(n0 + (o >> 7) + r8) * K + k0 + cg;
            load_lds16(gp, (f16*)((char*)sb + o));
        }
        __syncthreads();   // drains vmcnt (global_load_lds) + barrier

        #pragma unroll
        for (int kc = 0; kc < 2; ++kc) {
            f16x8 af[4], bf[NI];
            #pragma unroll
            for (int mi = 0; mi < 4; ++mi) {
                int ar = wm * 64 + mi * 16 + (lane & 15);
                af[mi] = *(const f16x8*)&sa[ar * 64 + ((((kc << 2) | (lane >> 4)) ^ (ar & 7)) << 3)];
            }
            #pragma unroll
            for (int ni = 0; ni < NI; ++ni) {
                int br = wn * (BN / 2) + ni * 16 + (lane & 15);
                bf[ni] = *(const f16x8*)&sb[br * 64 + ((((kc << 2) | (lane >> 4)) ^ (br & 7)) << 3)];
            }
            #pragma unroll
            for (int mi = 0; mi < 4; ++mi)
                #pragma unroll
                for (int ni = 0; ni < NI; ++ni)
                    acc[mi][ni] = __builtin_amdgcn_mfma_f32_16x16x32_f16(af[mi], bf[ni], acc[mi][ni], 0, 0, 0);
        }
        __syncthreads();   // protect LDS before next stage
    }

    // epilogue: C/D layout col = lane&15, row = (lane>>4)*4 + r
    const int crow0 = m0 + wm * 64 + (lane >> 4) * 4;
    const int ccol0 = n0 + wn * (BN / 2) + (lane & 15);
    if (EPI == 0) {
        f16* C = (f16*)Cout;
        #pragma unroll
        for (int mi = 0; mi < 4; ++mi)
            #pragma unroll
            for (int ni = 0; ni < NI; ++ni) {
                int col = ccol0 + ni * 16;
                float bv = bias[col];
                #pragma unroll
                for (int r2 = 0; r2 < 4; ++r2) {
                    float v = fast_tanh(acc[mi][ni][r2] + bv);
                    C[(size_t)(crow0 + mi * 16 + r2) * N + col] = (f16)v;
                }
            }
    } else {
        float* C = (float*)Cout + (size_t)blockIdx.z * M * N;
        #pragma unroll
        for (int mi = 0; mi < 4; ++mi)
            #pragma unroll
            for (int ni = 0; ni < NI; ++ni) {
                int col = ccol0 + ni * 16;
                float bv = (blockIdx.z == 0 && col < bias_n) ? bias[col] * 100.0f : 0.0f;
                #pragma unroll
                for (int r2 = 0; r2 < 4; ++r2) {
                    float v = acc[mi][ni][r2] * 100.0f + bv;
                    C[(size_t)(crow0 + mi * 16 + r2) * N + col] = v;
                }
            }
    }
}

// ---------------- GEMM2: 128x128 2-phase double-buffered NT GEMM, f16 -------
// C_f16 = tanh(A(16384x2048) @ W1(2048x2048)^T + b1)
// R2 post-mortem: 8-phase port failed twice (MfmaUtil 32-35% both with and
// without sched pinning) -> reverted to the verified 996 TF m97-class
// geometry, restructured as the T3/T4 "minimum 2-phase" recipe (catalog,
// refcheck'd m230/m248):
//   prologue: STAGE(buf0, t=0); syncthreads;
//   loop t:   STAGE(buf^1, t+1)   <- issued BEFORE compute
//             COMPUTE(buf)        <- ~32 MFMA + 24 ds_read hide the DMA
//             __syncthreads()     <- single vmcnt(0)+lgkm drain + barrier
//   epilogue: COMPUTE(last buf)
// Ledger: stage targets the buffer whose ds_reads completed before the
// PREVIOUS syncthreads (each wave's reads drain at its own lgkmcnt before
// the barrier); syncthreads' implicit vmcnt(0) certifies the staged buffer.
// One barrier per K-tile (was two). LDS 64 KiB -> 2 blocks/CU.
__global__ __launch_bounds__(256, 2) void gemm2_db(
    const f16* __restrict__ A, const f16* __restrict__ Bm,
    const float* __restrict__ bias, f16* __restrict__ C)
{
    constexpr int BM = 128, BK = 64, BN = 128, NI = 4;
    constexpr int N = HID, K = HID;
    constexpr int NT = K / BK;                  // 32 K-tiles
    __shared__ __align__(16) f16 sa0[BM * BK];
    __shared__ __align__(16) f16 sa1[BM * BK];
    __shared__ __align__(16) f16 sb0[BN * BK];
    __shared__ __align__(16) f16 sb1[BN * BK];

    const int tid  = threadIdx.x;
    const int lane = tid & 63;
    const int wave = tid >> 6;
    const int wm = wave >> 1, wn = wave & 1;

    // L2-locality block swizzle: 8 m-tiles per group, n fastest within group
    const int flat = blockIdx.x + blockIdx.y * gridDim.x;
    const int gsz  = 8 * gridDim.y;
    const int grp  = flat / gsz;
    const int rem  = flat - grp * gsz;
    const int m0 = (grp * 8 + (rem & 7)) * BM;
    const int n0 = (rem >> 3) * BN;

    f32x4 acc[4][NI];
    #pragma unroll
    for (int i = 0; i < 4; ++i)
        #pragma unroll
        for (int j = 0; j < NI; ++j) acc[i][j] = (f32x4){0.f, 0.f, 0.f, 0.f};

    const int r8 = lane >> 3;                        // row within 8-row staging group
    const int cg = (((lane & 7) ^ r8) << 3);         // swizzled global k-chunk (elems)

#define G2_STAGE(k0, sap, sbp) { \
    _Pragma("unroll") \
    for (int c = 0; c < (BM * BK * 2) / 4096; ++c) { \
        int o = c * 4096 + wave * 1024; \
        load_lds16(A + (size_t)(m0 + (o >> 7) + r8) * K + (k0) + cg, \
                   (f16*)((char*)(sap) + o)); \
    } \
    _Pragma("unroll") \
    for (int c = 0; c < (BN * BK * 2) / 4096; ++c) { \
        int o = c * 4096 + wave * 1024; \
        load_lds16(Bm + (size_t)(n0 + (o >> 7) + r8) * K + (k0) + cg, \
                   (f16*)((char*)(sbp) + o)); \
    } }

#define G2_COMPUTE(sap, sbp) { \
    _Pragma("unroll") \
    for (int kc = 0; kc < 2; ++kc) { \
        f16x8 af[4], bf[NI]; \
        _Pragma("unroll") \
        for (int mi = 0; mi < 4; ++mi) { \
            int ar = wm * 64 + mi * 16 + (lane & 15); \
            af[mi] = *(const f16x8*)&(sap)[ar * 64 + ((((kc << 2) | (lane >> 4)) ^ (ar & 7)) << 3)]; \
        } \
        _Pragma("unroll") \
        for (int ni = 0; ni < NI; ++ni) { \
            int br = wn * 64 + ni * 16 + (lane & 15); \
            bf[ni] = *(const f16x8*)&(sbp)[br * 64 + ((((kc << 2) | (lane >> 4)) ^ (br & 7)) << 3)]; \
        } \
        _Pragma("unroll") \
        for (int mi = 0; mi < 4; ++mi) \
            _Pragma("unroll") \
            for (int ni = 0; ni < NI; ++ni) \
                acc[mi][ni] = __builtin_amdgcn_mfma_f32_16x16x32_f16(af[mi], bf[ni], acc[mi][ni], 0, 0, 0); \
    } }

    // prologue: tile 0 -> buf0
    G2_STAGE(0, sa0, sb0);
    __syncthreads();                     // vmcnt(0) drain + barrier

    // main loop: 2 tiles per iteration, static buffer roles (no runtime cur)
    #pragma unroll 1
    for (int t = 0; t < NT - 2; t += 2) {
        // even tile in buf0; prefetch t+1 -> buf1
        G2_STAGE((t + 1) * BK, sa1, sb1);
        G2_COMPUTE(sa0, sb0);
        __syncthreads();
        // odd tile in buf1; prefetch t+2 -> buf0
        G2_STAGE((t + 2) * BK, sa0, sb0);
        G2_COMPUTE(sa1, sb1);
        __syncthreads();
    }
    // tail: tile NT-2 in buf0 (prefetch NT-1), then NT-1 in buf1
    G2_STAGE((NT - 1) * BK, sa1, sb1);
    G2_COMPUTE(sa0, sb0);
    __syncthreads();
    G2_COMPUTE(sa1, sb1);

#undef G2_STAGE
#undef G2_COMPUTE

    // epilogue: C/D layout col = lane&15, row = (lane>>4)*4 + r
    const int crow0 = m0 + wm * 64 + (lane >> 4) * 4;
    const int ccol0 = n0 + wn * 64 + (lane & 15);
    #pragma unroll
    for (int mi = 0; mi < 4; ++mi)
        #pragma unroll
        for (int ni = 0; ni < NI; ++ni) {
            int col = ccol0 + ni * 16;
            float bv = bias[col];
            #pragma unroll
            for (int r2 = 0; r2 < 4; ++r2) {
                float v = fast_tanh(acc[mi][ni][r2] + bv);
                C[(size_t)(crow0 + mi * 16 + r2) * N + col] = (f16)v;
            }
        }
}

// ---------------- GEMM1: A is fp32 (raw input), staged with in-reg convert ---
// C_f16 = tanh(A(16384x128_f32) @ W0q(2048x128_f16)^T + b0); K = 128 (2 iters)
__global__ __launch_bounds__(256, 2) void gemm1_f32a(
    const float* __restrict__ A, const f16* __restrict__ Bm,
    const float* __restrict__ bias, f16* __restrict__ C)
{
    constexpr int BM = 128, BK = 64, BN = 128, NI = 4;
    constexpr int N = HID, K = D_INP;
    __shared__ __align__(16) f16 sa[BM * BK];
    __shared__ __align__(16) f16 sb[BN * BK];

    const int tid  = threadIdx.x;
    const int lane = tid & 63;
    const int wave = tid >> 6;
    const int wm = wave >> 1, wn = wave & 1;

    const int flat = blockIdx.x + blockIdx.y * gridDim.x;
    const int gsz  = 8 * gridDim.y;
    const int grp  = flat / gsz;
    const int rem  = flat - grp * gsz;
    const int m0 = (grp * 8 + (rem & 7)) * BM;
    const int n0 = (rem >> 3) * BN;

    f32x4 acc[4][NI];
    #pragma unroll
    for (int i = 0; i < 4; ++i)
        #pragma unroll
        for (int j = 0; j < NI; ++j) acc[i][j] = (f32x4){0.f, 0.f, 0.f, 0.f};

    const int r8 = lane >> 3;
    const int cg = (((lane & 7) ^ r8) << 3);

    for (int k0 = 0; k0 < K; k0 += BK) {
        // A: fp32 global -> convert -> ds_write_b128 (lane-contiguous, conflict-free)
        #pragma unroll
        for (int c = 0; c < (BM * BK * 2) / 4096; ++c) {
            int o = c * 4096 + wave * 1024;
            const float* gp = A + (size_t)(m0 + (o >> 7) + r8) * K + k0 + cg;
            float4 v0 = *(const float4*)gp;
            float4 v1 = *(const float4*)(gp + 4);
            f16x8 h;
            h[0] = (f16)v0.x; h[1] = (f16)v0.y; h[2] = (f16)v0.z; h[3] = (f16)v0.w;
            h[4] = (f16)v1.x; h[5] = (f16)v1.y; h[6] = (f16)v1.z; h[7] = (f16)v1.w;
            *(f16x8*)((char*)sa + o + (lane << 4)) = h;
        }
        // B: pre-converted f16 via async DMA
        #pragma unroll
        for (int c = 0; c < (BN * BK * 2) / 4096; ++c) {
            int o = c * 4096 + wave * 1024;
            const f16* gp = Bm + (size_t)(n0 + (o >> 7) + r8) * K + k0 + cg;
            load_lds16(gp, (f16*)((char*)sb + o));
        }
        __syncthreads();

        #pragma unroll
        for (int kc = 0; kc < 2; ++kc) {
            f16x8 af[4], bf[NI];
            #pragma unroll
            for (int mi = 0; mi < 4; ++mi) {
                int ar = wm * 64 + mi * 16 + (lane & 15);
                af[mi] = *(const f16x8*)&sa[ar * 64 + ((((kc << 2) | (lane >> 4)) ^ (ar & 7)) << 3)];
            }
            #pragma unroll
            for (int ni = 0; ni < NI; ++ni) {
                int br = wn * 64 + ni * 16 + (lane & 15);
                bf[ni] = *(const f16x8*)&sb[br * 64 + ((((kc << 2) | (lane >> 4)) ^ (br & 7)) << 3)];
            }
            #pragma unroll
            for (int mi = 0; mi < 4; ++mi)
                #pragma unroll
                for (int ni = 0; ni < NI; ++ni)
                    acc[mi][ni] = __builtin_amdgcn_mfma_f32_16x16x32_f16(af[mi], bf[ni], acc[mi][ni], 0, 0, 0);
        }
        __syncthreads();
    }

    const int crow0 = m0 + wm * 64 + (lane >> 4) * 4;
    const int ccol0 = n0 + wn * 64 + (lane & 15);
    #pragma unroll
    for (int mi = 0; mi < 4; ++mi)
        #pragma unroll
        for (int ni = 0; ni < NI; ++ni) {
            int col = ccol0 + ni * 16;
            float bv = bias[col];
            #pragma unroll
            for (int r2 = 0; r2 < 4; ++r2) {
                float v = fast_tanh(acc[mi][ni][r2] + bv);
                C[(size_t)(crow0 + mi * 16 + r2) * N + col] = (f16)v;
            }
        }
}

// ---------------- DMP Euler integration (sums NZ3 partial slices) -----------
// out3p: (NZ3, B, 64) partial MLP outputs; input: (B, 128); out: (B, 9, 10)
__global__ __launch_bounds__(256) void integrate_kernel(
    const float* __restrict__ out3p, const float* __restrict__ input,
    float* __restrict__ out)
{
    __shared__ float g[500];
    {
        int k = threadIdx.x;
        if (k < 100) {
            // x after k+1 steps of x *= 0.99  (closed form)
            float x = expf(-0.010050335853501441f * (float)(k + 1));
            float psi[5], ssum = 0.0f;
            #pragma unroll
            for (int n = 0; n < 5; ++n) {
                float c = expf(-0.25f * (float)n);
                float h = 11.180339887498949f / c;   // N^1.5 / c / A_X
                float dx = x - c;
                psi[n] = expf(-h * dx * dx);
                ssum += psi[n];
            }
            float inv = x / ssum;
            #pragma unroll
            for (int n = 0; n < 5; ++n) g[k * 5 + n] = psi[n] * inv;
        }
    }
    __syncthreads();

    int r = blockIdx.x * 256 + threadIdx.x;      // 0 .. B*9-1
    int b = r / DIMS, d = r - b * DIMS;

    float goal = 0.f, w0 = 0.f, w1 = 0.f, w2 = 0.f, w3 = 0.f, w4 = 0.f;
    #pragma unroll
    for (int z = 0; z < NZ3; ++z) {
        const float* ob = out3p + (size_t)z * B_SZ * OUTP + (size_t)b * OUTP;
        goal += ob[d];
        w0 += ob[DIMS + d * 5 + 0];
        w1 += ob[DIMS + d * 5 + 1];
        w2 += ob[DIMS + d * 5 + 2];
        w3 += ob[DIMS + d * 5 + 3];
        w4 += ob[DIMS + d * 5 + 4];
    }

    float y = input[(size_t)b * D_INP + 7 + d];    // y0
    float z = input[(size_t)b * D_INP + 22 + d];   // dy0 * TAU (TAU=1)
    const float scale = goal - y;

    float prev = y;
    float* op = out + (size_t)b * (DIMS * 10) + d * 10;
    int j = 0;
    for (int k = 0; k < 100; ++k) {
        const float* gk = &g[k * 5];
        float fx = scale * (w0 * gk[0] + w1 * gk[1] + w2 * gk[2] + w3 * gk[3] + w4 * gk[4]);
        float dz = 25.0f * (6.25f * (goal - y) - z) + fx;   // A_Z=25, B_Z=6.25
        y = y + z * 0.01f;     // dy = z (old z), y += dy*DT
        z = z + dz * 0.01f;
        if ((k % 10) == 9) { op[j] = y - prev; prev = y; ++j; }
    }
}

// ---------------- launch ----------------
extern "C" void kernel_launch(void* const* d_in, const int* in_sizes, int n_in,
                              void* d_out, int out_size, void* d_ws, size_t ws_size,
                              hipStream_t stream) {
    (void)in_sizes; (void)n_in; (void)out_size; (void)ws_size;
    const float* input = (const float*)d_in[0];
    const float* W0 = (const float*)d_in[1];
    const float* b0 = (const float*)d_in[2];
    const float* W1 = (const float*)d_in[3];
    const float* b1 = (const float*)d_in[4];
    const float* Wl = (const float*)d_in[5];
    const float* bl = (const float*)d_in[6];
    float* out = (float*)d_out;

    // workspace layout (all 16B-aligned by construction)
    f16* w0q = (f16*)d_ws;                                // 2048*128
    f16* w1q = w0q + (size_t)HID * D_INP;                 // 2048*2048
    f16* wlq = w1q + (size_t)HID * HID;                   // 64*2048
    f16* h1  = wlq + (size_t)OUTP * HID;                  // 16384*2048
    f16* h2  = h1 + (size_t)B_SZ * HID;                   // 16384*2048
    // GEMM3 partial slices overlay h1 (dead after GEMM2): NZ3 * 16384 * 64 f32
    float* out3p = (float*)h1;

    int n4_total = N4_W0 + N4_W1 + N4_WL;
    cvt_fused_kernel<<<(n4_total + 255) / 256, 256, 0, stream>>>(
        W0, W1, Wl, w0q, w1q, wlq);

    // h1 = tanh(input @ W0^T + b0), A staged from fp32 directly
    gemm1_f32a<<<dim3(B_SZ / 128, HID / 128), 256, 0, stream>>>(
        input, w0q, b0, h1);
    // h2 = tanh(h1 @ W1^T + b1) — 2-phase double-buffered 128^2 kernel
    gemm2_db<<<dim3(B_SZ / 128, HID / 128), 256, 0, stream>>>(
        h1, w1q, b1, h2);
    // out3p[z] = (h2 @ Wl^T)*100 slices (+bl*100 on z0); N padded to 64
    gemm_nt<64, 1><<<dim3(B_SZ / 128, 1, NZ3), 256, 0, stream>>>(
        h2, wlq, bl, (void*)out3p, B_SZ, OUTP, HID, OUTC);

    integrate_kernel<<<B_SZ * DIMS / 256, 256, 0, stream>>>(out3p, input, out);
}